// Round 11
// baseline (258.288 us; speedup 1.0000x reference)
//
#include <hip/hip_runtime.h>
#include <hip/hip_bf16.h>
#include <math.h>

#define N_NODES 100000
#define N_EDGES 400000
#define N_PAIRS 100000
#define NBINS   200000   // (rel, dst) bins

typedef short short8_t __attribute__((ext_vector_type(8)));
typedef float f32x4    __attribute__((ext_vector_type(4)));

__device__ __forceinline__ ushort f2bf(float f) {
    uint u = __float_as_uint(f);
    u += 0x7fffu + ((u >> 16) & 1u);          // RNE
    return (ushort)(u >> 16);
}
__device__ __forceinline__ float bf2f(ushort b) {
    return __uint_as_float(((uint)b) << 16);
}
__device__ __forceinline__ uint packbf(float a, float b) {
    return (uint)f2bf(a) | ((uint)f2bf(b) << 16);
}
__device__ __forceinline__ float lo16(uint v) { return bf2f((ushort)(v & 0xffffu)); }
__device__ __forceinline__ float hi16(uint v) { return bf2f((ushort)(v >> 16)); }

#define GLDS16(gp, lp) \
    __builtin_amdgcn_global_load_lds((const __attribute__((address_space(1))) uint*)(gp), \
                                     (__attribute__((address_space(3))) uint*)(lp), 16, 0, 0)

template<int N> __device__ __forceinline__ void waitvm() {
    if constexpr (N == 0)      asm volatile("s_waitcnt vmcnt(0)" ::: "memory");
    else if constexpr (N == 4) asm volatile("s_waitcnt vmcnt(4)" ::: "memory");
    else if constexpr (N == 8) asm volatile("s_waitcnt vmcnt(8)" ::: "memory");
}

// ---------------------------------------------------------------------------
// prep: fuses x0/x1 bf16 casts, the 4 weight repacks, and cnt zeroing.
// ---------------------------------------------------------------------------
#define PREP_TOTAL 2671184
__global__ void prep_kernel(const float* __restrict__ x0, const float* __restrict__ x1,
                            const float* __restrict__ l0w, const float* __restrict__ l1w,
                            const float* __restrict__ c1r, const float* __restrict__ c1w,
                            const float* __restrict__ c2r, const float* __restrict__ c2w,
                            ushort* __restrict__ x0bf, ushort* __restrict__ x1bf,
                            ushort* __restrict__ wl0, ushort* __restrict__ wl1,
                            ushort* __restrict__ wc1, ushort* __restrict__ wc2,
                            int* __restrict__ cnt) {
    int i = blockIdx.x * 256 + threadIdx.x;
    const int stride = gridDim.x * 256;
    for (; i < PREP_TOTAL; i += stride) {
        int j = i;
        if (j < 1600000) {
            float4 v = ((const float4*)x0)[j];
            ushort4 o; o.x = f2bf(v.x); o.y = f2bf(v.y); o.z = f2bf(v.z); o.w = f2bf(v.w);
            ((ushort4*)x0bf)[j] = o;
        } else if ((j -= 1600000) < 800000) {
            float4 v = ((const float4*)x1)[j];
            ushort4 o; o.x = f2bf(v.x); o.y = f2bf(v.y); o.z = f2bf(v.z); o.w = f2bf(v.w);
            ((ushort4*)x1bf)[j] = o;
        } else if ((j -= 800000) < 16384) {
            int n = j >> 7, k = j & 127;
            wl0[j] = f2bf(l0w[(size_t)k * 128 + n]);
        } else if ((j -= 16384) < 8192) {
            int n = j >> 6, k = j & 63;
            wl1[j] = f2bf(l1w[(size_t)k * 128 + n]);
        } else if ((j -= 8192) < 98304) {
            int n = j / 384, k = j % 384;
            float v = (k < 128) ? c1r[(size_t)k * 256 + n] : c1w[(size_t)(k - 128) * 256 + n];
            wc1[(size_t)n * 384 + k] = f2bf(v);
        } else if ((j -= 98304) < 98304) {
            int n = j >> 8, k = j & 255;
            float v = (n < 128) ? c2r[(size_t)k * 128 + n]
                                : c2w[((size_t)((n >> 7) - 1) * 256 + k) * 128 + (n & 127)];
            wc2[(size_t)n * 256 + k] = f2bf(v);
        } else {
            j -= 98304;
            ((int4*)cnt)[j] = make_int4(0, 0, 0, 0);
        }
    }
}

// ---------------------------------------------------------------------------
// CSR build: histogram -> exclusive scan (3 kernels) -> fill
// ---------------------------------------------------------------------------
__global__ void hist_kernel(const int* __restrict__ dst, const int* __restrict__ et,
                            int* __restrict__ cnt) {
    int e = blockIdx.x * 256 + threadIdx.x;
    if (e < N_EDGES) atomicAdd(&cnt[et[e] * N_NODES + dst[e]], 1);
}

__global__ __launch_bounds__(1024) void scan1_kernel(const int* __restrict__ cnt,
                                                     int* __restrict__ ptr,
                                                     int* __restrict__ aux) {
    __shared__ int s[1024];
    int i = blockIdx.x * 1024 + threadIdx.x;
    int v = (i < NBINS) ? cnt[i] : 0;
    s[threadIdx.x] = v;
    __syncthreads();
    for (int off = 1; off < 1024; off <<= 1) {
        int t = (threadIdx.x >= off) ? s[threadIdx.x - off] : 0;
        __syncthreads();
        s[threadIdx.x] += t;
        __syncthreads();
    }
    if (i < NBINS) ptr[i] = s[threadIdx.x] - v;          // block-exclusive
    if (threadIdx.x == 1023) aux[blockIdx.x] = s[1023];  // block total
}

__global__ void scan2_kernel(int* __restrict__ aux, int nblk) {
    __shared__ int s[256];
    int v = (threadIdx.x < nblk) ? aux[threadIdx.x] : 0;
    s[threadIdx.x] = v;
    __syncthreads();
    for (int off = 1; off < 256; off <<= 1) {
        int t = (threadIdx.x >= off) ? s[threadIdx.x - off] : 0;
        __syncthreads();
        s[threadIdx.x] += t;
        __syncthreads();
    }
    if (threadIdx.x < nblk) aux[threadIdx.x] = s[threadIdx.x] - v;  // exclusive
}

__global__ void scan3_kernel(const int* __restrict__ aux, int* __restrict__ ptr,
                             int* __restrict__ cursor) {
    int i = blockIdx.x * 256 + threadIdx.x;
    if (i < NBINS) {
        int val = ptr[i] + aux[i >> 10];
        ptr[i] = val;
        cursor[i] = val;
    }
    if (i == 0) ptr[NBINS] = N_EDGES;
}

__global__ void fill_kernel(const int* __restrict__ src, const int* __restrict__ dst,
                            const int* __restrict__ et, int* __restrict__ cursor,
                            int* __restrict__ esorted) {
    int e = blockIdx.x * 256 + threadIdx.x;
    if (e < N_EDGES) {
        int b = et[e] * N_NODES + dst[e];
        int pos = atomicAdd(&cursor[b], 1);
        esorted[pos] = src[e];
    }
}

// ---------------------------------------------------------------------------
// Layer-1 gather-mean: one wave per TWO dst nodes (2 independent latency
// chains in flight), both relations, k-step-2 (8 guarded loads per iter).
// ---------------------------------------------------------------------------
__global__ void gather1_kernel(const int* __restrict__ ptr, const int* __restrict__ es,
                               ushort* __restrict__ A1) {
    int d0 = (blockIdx.x * 4 + (threadIdx.x >> 6)) * 2;
    if (d0 >= N_NODES) return;
    int lane = threadIdx.x & 63;
    int p0[2], n0[2], q0[2], n1[2];
#pragma unroll
    for (int u = 0; u < 2; u++) {
        p0[u] = ptr[d0 + u];           n0[u] = ptr[d0 + u + 1] - p0[u];
        q0[u] = ptr[N_NODES + d0 + u]; n1[u] = ptr[N_NODES + d0 + u + 1] - q0[u];
    }
    float a0[2] = {0, 0}, a1[2] = {0, 0}, b0[2] = {0, 0}, b1[2] = {0, 0};
    int n = n0[0] > n0[1] ? n0[0] : n0[1];
    int m2 = n1[0] > n1[1] ? n1[0] : n1[1];
    n = n > m2 ? n : m2;
    for (int k = 0; k < n; k += 2) {
        uint v0[2] = {0, 0}, v1[2] = {0, 0}, v2[2] = {0, 0}, v3[2] = {0, 0};
#pragma unroll
        for (int u = 0; u < 2; u++) {
            if (k     < n0[u]) v0[u] = *(const uint*)(A1 + (size_t)es[p0[u] + k]     * 384 + lane * 2);
            if (k + 1 < n0[u]) v1[u] = *(const uint*)(A1 + (size_t)es[p0[u] + k + 1] * 384 + lane * 2);
            if (k     < n1[u]) v2[u] = *(const uint*)(A1 + (size_t)es[q0[u] + k]     * 384 + lane * 2);
            if (k + 1 < n1[u]) v3[u] = *(const uint*)(A1 + (size_t)es[q0[u] + k + 1] * 384 + lane * 2);
        }
#pragma unroll
        for (int u = 0; u < 2; u++) {
            a0[u] += lo16(v0[u]) + lo16(v1[u]);
            a1[u] += hi16(v0[u]) + hi16(v1[u]);
            b0[u] += lo16(v2[u]) + lo16(v3[u]);
            b1[u] += hi16(v2[u]) + hi16(v3[u]);
        }
    }
#pragma unroll
    for (int u = 0; u < 2; u++) {
        float i0 = n0[u] ? 1.0f / (float)n0[u] : 0.0f;
        float i1 = n1[u] ? 1.0f / (float)n1[u] : 0.0f;
        uint* row = (uint*)(A1 + (size_t)(d0 + u) * 384);
        row[64  + lane] = packbf(a0[u] * i0, a1[u] * i0);
        row[128 + lane] = packbf(b0[u] * i1, b1[u] * i1);
    }
}

// ---------------------------------------------------------------------------
// Layer-2 combine: two dst nodes per wave.
// z[d] = H[d][0:128] + mean_r0 H[s][128:256] + mean_r1 H[s][256:384], bf16 out.
// ---------------------------------------------------------------------------
__global__ void combine2_kernel(const int* __restrict__ ptr, const int* __restrict__ es,
                                const ushort* __restrict__ H, ushort* __restrict__ zb) {
    int d0 = (blockIdx.x * 4 + (threadIdx.x >> 6)) * 2;
    if (d0 >= N_NODES) return;
    int lane = threadIdx.x & 63;
    int p0[2], n0[2], q0[2], n1[2];
#pragma unroll
    for (int u = 0; u < 2; u++) {
        p0[u] = ptr[d0 + u];           n0[u] = ptr[d0 + u + 1] - p0[u];
        q0[u] = ptr[N_NODES + d0 + u]; n1[u] = ptr[N_NODES + d0 + u + 1] - q0[u];
    }
    uint rv[2];
    rv[0] = *(const uint*)(H + (size_t)d0 * 384 + lane * 2);
    rv[1] = *(const uint*)(H + (size_t)(d0 + 1) * 384 + lane * 2);
    float a0[2] = {0, 0}, a1[2] = {0, 0}, b0[2] = {0, 0}, b1[2] = {0, 0};
    int n = n0[0] > n0[1] ? n0[0] : n0[1];
    int m2 = n1[0] > n1[1] ? n1[0] : n1[1];
    n = n > m2 ? n : m2;
    for (int k = 0; k < n; k += 2) {
        uint v0[2] = {0, 0}, v1[2] = {0, 0}, v2[2] = {0, 0}, v3[2] = {0, 0};
#pragma unroll
        for (int u = 0; u < 2; u++) {
            if (k     < n0[u]) v0[u] = *(const uint*)(H + (size_t)es[p0[u] + k]     * 384 + 128 + lane * 2);
            if (k + 1 < n0[u]) v1[u] = *(const uint*)(H + (size_t)es[p0[u] + k + 1] * 384 + 128 + lane * 2);
            if (k     < n1[u]) v2[u] = *(const uint*)(H + (size_t)es[q0[u] + k]     * 384 + 256 + lane * 2);
            if (k + 1 < n1[u]) v3[u] = *(const uint*)(H + (size_t)es[q0[u] + k + 1] * 384 + 256 + lane * 2);
        }
#pragma unroll
        for (int u = 0; u < 2; u++) {
            a0[u] += lo16(v0[u]) + lo16(v1[u]);
            a1[u] += hi16(v0[u]) + hi16(v1[u]);
            b0[u] += lo16(v2[u]) + lo16(v3[u]);
            b1[u] += hi16(v2[u]) + hi16(v3[u]);
        }
    }
#pragma unroll
    for (int u = 0; u < 2; u++) {
        float i0 = n0[u] ? 1.0f / (float)n0[u] : 0.0f;
        float i1 = n1[u] ? 1.0f / (float)n1[u] : 0.0f;
        ((uint*)(zb + (size_t)(d0 + u) * 128))[lane] =
            packbf(lo16(rv[u]) + a0[u] * i0 + b0[u] * i1,
                   hi16(rv[u]) + a1[u] * i0 + b1[u] * i1);
    }
}

// ---------------------------------------------------------------------------
// MFMA GEMM body: 128x128 tile, 256 threads / 4 waves (2x2 quadrants), 3-slot
// LDS pipeline with counted vmcnt, global_load_lds width-16, XOR-swizzled LDS.
// SWAPPED-OPERAND MFMA: acc = mfma(B_frag, A_frag, acc) -> D holds out^T
// fragments, so each thread's 4 acc regs are 4 CONSECUTIVE output columns
// -> 8B uint2 stores (16 stores/thread instead of 64 x 2B).
// ---------------------------------------------------------------------------
template<int KTOT, int OST, int BIASN, bool RELU>
__device__ __forceinline__
void gemm_body(const ushort* __restrict__ A, const ushort* __restrict__ Wt,
               const float* __restrict__ bias, ushort* __restrict__ outp,
               int nrows, int m0, int n0) {
    __shared__ short As[3][128 * 32];
    __shared__ short Bs[3][128 * 32];
    const int t = threadIdx.x;
    const int lane = t & 63, w = t >> 6;
    const int wr = w >> 1, wc = w & 1;
    const int l15 = lane & 15, l4 = lane >> 4;

    const int arow = t >> 2;
    const int swc = ((t & 3) ^ ((arow >> 1) & 3)) * 8;
    int rg0 = m0 + arow;      if (rg0 >= nrows) rg0 = nrows - 1;
    int rg1 = m0 + arow + 64; if (rg1 >= nrows) rg1 = nrows - 1;
    const ushort* ap0 = A + (size_t)rg0 * KTOT + swc;
    const ushort* ap1 = A + (size_t)rg1 * KTOT + swc;
    const ushort* bp0 = Wt + (size_t)(n0 + arow) * KTOT + swc;
    const ushort* bp1 = Wt + (size_t)(n0 + arow + 64) * KTOT + swc;

#define STAGE(slot, kg) do { \
        GLDS16(ap0 + (kg), &As[slot][t * 8]); \
        GLDS16(ap1 + (kg), &As[slot][(t + 256) * 8]); \
        GLDS16(bp0 + (kg), &Bs[slot][t * 8]); \
        GLDS16(bp1 + (kg), &Bs[slot][(t + 256) * 8]); \
    } while (0)

    // acc[i][j]: output rows m0+wr*64+i*16+l15, cols n0+wc*64+j*16+l4*4+{0..3}
    f32x4 acc[4][4];
#pragma unroll
    for (int j = 0; j < 4; j++) {
        int col = n0 + wc * 64 + j * 16 + l4 * 4;   // multiple of 4; BIASN mult of 4
        f32x4 bv;
        if (col < BIASN) bv = *(const f32x4*)(bias + col);
        else             bv = (f32x4){0.0f, 0.0f, 0.0f, 0.0f};
#pragma unroll
        for (int i = 0; i < 4; i++) acc[i][j] = bv;
    }

    const int xr = (l4 ^ ((l15 >> 1) & 3)) * 8;

    constexpr int NSTEP = KTOT / 32;
    STAGE(0, 0);
    if (NSTEP > 1) STAGE(1, 32);
    for (int ks = 0; ks < NSTEP; ks++) {
        const int slot = ks % 3;
        if (ks + 2 < NSTEP) {
            STAGE((ks + 2) % 3, (ks + 2) * 32);
            waitvm<8>();
        } else if (ks + 1 < NSTEP) {
            waitvm<4>();
        } else {
            waitvm<0>();
        }
        asm volatile("s_barrier" ::: "memory");
        short8_t af[4], bfr[4];
#pragma unroll
        for (int i = 0; i < 4; i++)
            af[i] = *(short8_t*)&As[slot][(wr * 64 + i * 16 + l15) * 32 + xr];
#pragma unroll
        for (int j = 0; j < 4; j++)
            bfr[j] = *(short8_t*)&Bs[slot][(wc * 64 + j * 16 + l15) * 32 + xr];
#pragma unroll
        for (int i = 0; i < 4; i++)
#pragma unroll
            for (int j = 0; j < 4; j++)
                acc[i][j] = __builtin_amdgcn_mfma_f32_16x16x32_bf16(bfr[j], af[i], acc[i][j], 0, 0, 0);
        asm volatile("s_barrier" ::: "memory");
    }
#undef STAGE

#pragma unroll
    for (int i = 0; i < 4; i++) {
        int row = m0 + wr * 64 + i * 16 + l15;
        if (row < nrows) {
#pragma unroll
            for (int j = 0; j < 4; j++) {
                int col = n0 + wc * 64 + j * 16 + l4 * 4;
                f32x4 v = acc[i][j];
                if (RELU) {
#pragma unroll
                    for (int r = 0; r < 4; r++) v[r] = fmaxf(v[r], 0.0f);
                }
                uint2 o;
                o.x = packbf(v[0], v[1]);
                o.y = packbf(v[2], v[3]);
                *(uint2*)(outp + (size_t)row * OST + col) = o;
            }
        }
    }
}

// GEMM wrapper with XCD-bijective swizzle + N-panel-fastest work order.
template<int KTOT, int NP, int OST, int BIASN, bool RELU>
__global__ __launch_bounds__(256)
void mfma_gemm_kernel(const ushort* __restrict__ A, const ushort* __restrict__ Wt,
                      const float* __restrict__ bias, ushort* __restrict__ outp,
                      int nrows, int mtiles) {
    const int nwg = mtiles * NP;
    const int q = nwg >> 3, r = nwg & 7;
    const int orig = blockIdx.x;
    const int xcd = orig & 7;
    const int work = (xcd < r ? xcd * (q + 1) : r * (q + 1) + (xcd - r) * q) + (orig >> 3);
    const int mt = work / NP;
    gemm_body<KTOT, OST, BIASN, RELU>(A, Wt, bias, outp, nrows,
                                      mt * 128, (work - mt * NP) * 128);
}

// Both input projections in one launch: blocks [0,391) type0 (K=128),
// [391,782) type1 (K=64). Output into A1 x-slab (stride 384).
__global__ __launch_bounds__(256)
void proj_kernel(const ushort* __restrict__ x0bf, const ushort* __restrict__ x1bf,
                 const ushort* __restrict__ wl0, const ushort* __restrict__ wl1,
                 const float* __restrict__ l0b, const float* __restrict__ l1b,
                 ushort* __restrict__ A1) {
    if (blockIdx.x < 391)
        gemm_body<128, 384, 128, false>(x0bf, wl0, l0b, A1, 50000,
                                        blockIdx.x * 128, 0);
    else
        gemm_body<64, 384, 128, false>(x1bf, wl1, l1b, A1 + (size_t)50000 * 384, 50000,
                                       (blockIdx.x - 391) * 128, 0);
}

// ---------------------------------------------------------------------------
// Decode: two pairs per wave (4 independent row loads in flight).
// out[p] = sigmoid(z[s]·fcw[0:128] + z[d]·fcw[128:256] + fcb), z bf16.
// ---------------------------------------------------------------------------
__global__ void decode_kernel(const ushort* __restrict__ zb, const int* __restrict__ dec,
                              const float* __restrict__ fcw, const float* __restrict__ fcb,
                              float* __restrict__ out) {
    int p0 = (blockIdx.x * 4 + (threadIdx.x >> 6)) * 2;
    if (p0 >= N_PAIRS) return;
    int lane = threadIdx.x & 63;
    float ws0 = fcw[2 * lane],       ws1 = fcw[2 * lane + 1];
    float wd0 = fcw[128 + 2 * lane], wd1 = fcw[128 + 2 * lane + 1];
    int s0 = dec[p0],     dd0 = dec[N_PAIRS + p0];
    int s1 = dec[p0 + 1], dd1 = dec[N_PAIRS + p0 + 1];
    uint vs0 = ((const uint*)(zb + (size_t)s0  * 128))[lane];
    uint vd0 = ((const uint*)(zb + (size_t)dd0 * 128))[lane];
    uint vs1 = ((const uint*)(zb + (size_t)s1  * 128))[lane];
    uint vd1 = ((const uint*)(zb + (size_t)dd1 * 128))[lane];
    float v0 = lo16(vs0) * ws0 + hi16(vs0) * ws1 + lo16(vd0) * wd0 + hi16(vd0) * wd1;
    float v1 = lo16(vs1) * ws0 + hi16(vs1) * ws1 + lo16(vd1) * wd0 + hi16(vd1) * wd1;
#pragma unroll
    for (int off = 32; off > 0; off >>= 1) {
        v0 += __shfl_down(v0, off);
        v1 += __shfl_down(v1, off);
    }
    if (lane == 0) {
        float fb = fcb[0];
        out[p0]     = 1.0f / (1.0f + expf(-(v0 + fb)));
        out[p0 + 1] = 1.0f / (1.0f + expf(-(v1 + fb)));
    }
}

// ---------------------------------------------------------------------------
extern "C" void kernel_launch(void* const* d_in, const int* in_sizes, int n_in,
                              void* d_out, int out_size, void* d_ws, size_t ws_size,
                              hipStream_t stream) {
    const float* x0        = (const float*)d_in[0];
    const float* x1        = (const float*)d_in[1];
    const int*   edge_idx  = (const int*)  d_in[2];
    const int*   edge_type = (const int*)  d_in[3];
    const int*   dec_index = (const int*)  d_in[4];
    const float* lin0_w    = (const float*)d_in[5];
    const float* lin0_b    = (const float*)d_in[6];
    const float* lin1_w    = (const float*)d_in[7];
    const float* lin1_b    = (const float*)d_in[8];
    const float* conv1_w   = (const float*)d_in[9];
    const float* conv1_root= (const float*)d_in[10];
    const float* conv1_b   = (const float*)d_in[11];
    const float* conv2_w   = (const float*)d_in[12];
    const float* conv2_root= (const float*)d_in[13];
    const float* conv2_b   = (const float*)d_in[14];
    const float* fc_w      = (const float*)d_in[15];
    const float* fc_b      = (const float*)d_in[16];
    float* out = (float*)d_out;

    // ---- workspace layout (bytes), ~151.6 MB; H aliases A1, zb aliases y1 ----
    char* W = (char*)d_ws;
    ushort* A1    = (ushort*)(W + 0);            // 76,800,000 B [100k][384] = [x|agg0|agg1]
    ushort* H     = (ushort*)(W + 0);            // alias (A1 dead after gemm1)
    ushort* y1    = (ushort*)(W + 76800000);     // 51,200,000 B [100k][256]
    ushort* zb    = (ushort*)(W + 76800000);     // alias: [100k][128] bf16 (y1 dead after gemm2)
    int*    cnt   = (int*)   (W + 128000000);
    int*    ptrb  = (int*)   (W + 128800000);
    int*    cursor= (int*)   (W + 129600016);
    int*    aux   = (int*)   (W + 130400016);
    int*    esort = (int*)   (W + 130404112);
    ushort* wc1   = (ushort*)(W + 132004112);    // [256][384] bf16
    ushort* wc2   = (ushort*)(W + 132200720);    // [384][256] bf16
    ushort* wl0   = (ushort*)(W + 132397328);    // [128][128] bf16
    ushort* wl1   = (ushort*)(W + 132430096);    // [128][64]  bf16
    ushort* x0bf  = (ushort*)(W + 132446480);    // [50000][128] bf16
    ushort* x1bf  = (ushort*)(W + 145246480);    // [50000][64]  bf16

    const int* esrc = edge_idx;
    const int* edst = edge_idx + N_EDGES;

    // 1) fused prep: casts, weight repacks, cnt zero
    prep_kernel<<<2048, 256, 0, stream>>>(x0, x1, lin0_w, lin1_w,
                                          conv1_root, conv1_w, conv2_root, conv2_w,
                                          x0bf, x1bf, wl0, wl1, wc1, wc2, cnt);

    // 2) CSR build over (rel,dst)
    hist_kernel<<<(N_EDGES + 255) / 256, 256, 0, stream>>>(edst, edge_type, cnt);
    scan1_kernel<<<(NBINS + 1023) / 1024, 1024, 0, stream>>>(cnt, ptrb, aux);
    scan2_kernel<<<1, 256, 0, stream>>>(aux, (NBINS + 1023) / 1024);
    scan3_kernel<<<(NBINS + 255) / 256, 256, 0, stream>>>(aux, ptrb, cursor);
    fill_kernel<<<(N_EDGES + 255) / 256, 256, 0, stream>>>(esrc, edst, edge_type,
                                                           cursor, esort);

    // 3) both input projections -> A1 x-slab (cols 0:128, stride 384)
    proj_kernel<<<782, 256, 0, stream>>>(x0bf, x1bf, wl0, wl1, lin0_b, lin1_b, A1);

    // 4) layer 1: per-dst gather-mean into A1 agg slabs, then GEMM+ReLU -> y1
    gather1_kernel<<<12500, 256, 0, stream>>>(ptrb, esort, A1);
    mfma_gemm_kernel<384, 2, 256, 256, true>
        <<<1564, 256, 0, stream>>>(A1, wc1, conv1_b, y1, N_NODES, 782);

    // 5) layer 2: GEMM y1 @ [root2|W0|W1] -> H (aliases A1), then combine -> zb
    mfma_gemm_kernel<256, 3, 384, 128, false>
        <<<2346, 256, 0, stream>>>(y1, wc2, conv2_b, H, N_NODES, 782);
    combine2_kernel<<<12500, 256, 0, stream>>>(ptrb, esort, H, zb);

    // 6) decode
    decode_kernel<<<12500, 256, 0, stream>>>(zb, dec_index, fc_w, fc_b, out);
}

// Round 12
// 244.587 us; speedup vs baseline: 1.0560x; 1.0560x over previous
//
#include <hip/hip_runtime.h>
#include <hip/hip_bf16.h>
#include <math.h>

#define N_NODES 100000
#define N_EDGES 400000
#define N_PAIRS 100000
#define NBINS   200000   // (rel, dst) bins

typedef short short8_t __attribute__((ext_vector_type(8)));
typedef float f32x4    __attribute__((ext_vector_type(4)));

__device__ __forceinline__ ushort f2bf(float f) {
    uint u = __float_as_uint(f);
    u += 0x7fffu + ((u >> 16) & 1u);          // RNE
    return (ushort)(u >> 16);
}
__device__ __forceinline__ float bf2f(ushort b) {
    return __uint_as_float(((uint)b) << 16);
}
__device__ __forceinline__ uint packbf(float a, float b) {
    return (uint)f2bf(a) | ((uint)f2bf(b) << 16);
}
__device__ __forceinline__ float lo16(uint v) { return bf2f((ushort)(v & 0xffffu)); }
__device__ __forceinline__ float hi16(uint v) { return bf2f((ushort)(v >> 16)); }

#define GLDS16(gp, lp) \
    __builtin_amdgcn_global_load_lds((const __attribute__((address_space(1))) uint*)(gp), \
                                     (__attribute__((address_space(3))) uint*)(lp), 16, 0, 0)

template<int N> __device__ __forceinline__ void waitvm() {
    if constexpr (N == 0)      asm volatile("s_waitcnt vmcnt(0)" ::: "memory");
    else if constexpr (N == 4) asm volatile("s_waitcnt vmcnt(4)" ::: "memory");
    else if constexpr (N == 8) asm volatile("s_waitcnt vmcnt(8)" ::: "memory");
}

// ---------------------------------------------------------------------------
// prep: fuses x0/x1 bf16 casts, the 4 weight repacks, and cnt zeroing.
// ---------------------------------------------------------------------------
#define PREP_TOTAL 2671184
__global__ void prep_kernel(const float* __restrict__ x0, const float* __restrict__ x1,
                            const float* __restrict__ l0w, const float* __restrict__ l1w,
                            const float* __restrict__ c1r, const float* __restrict__ c1w,
                            const float* __restrict__ c2r, const float* __restrict__ c2w,
                            ushort* __restrict__ x0bf, ushort* __restrict__ x1bf,
                            ushort* __restrict__ wl0, ushort* __restrict__ wl1,
                            ushort* __restrict__ wc1, ushort* __restrict__ wc2,
                            int* __restrict__ cnt) {
    int i = blockIdx.x * 256 + threadIdx.x;
    const int stride = gridDim.x * 256;
    for (; i < PREP_TOTAL; i += stride) {
        int j = i;
        if (j < 1600000) {
            float4 v = ((const float4*)x0)[j];
            ushort4 o; o.x = f2bf(v.x); o.y = f2bf(v.y); o.z = f2bf(v.z); o.w = f2bf(v.w);
            ((ushort4*)x0bf)[j] = o;
        } else if ((j -= 1600000) < 800000) {
            float4 v = ((const float4*)x1)[j];
            ushort4 o; o.x = f2bf(v.x); o.y = f2bf(v.y); o.z = f2bf(v.z); o.w = f2bf(v.w);
            ((ushort4*)x1bf)[j] = o;
        } else if ((j -= 800000) < 16384) {
            int n = j >> 7, k = j & 127;
            wl0[j] = f2bf(l0w[(size_t)k * 128 + n]);
        } else if ((j -= 16384) < 8192) {
            int n = j >> 6, k = j & 63;
            wl1[j] = f2bf(l1w[(size_t)k * 128 + n]);
        } else if ((j -= 8192) < 98304) {
            int n = j / 384, k = j % 384;
            float v = (k < 128) ? c1r[(size_t)k * 256 + n] : c1w[(size_t)(k - 128) * 256 + n];
            wc1[(size_t)n * 384 + k] = f2bf(v);
        } else if ((j -= 98304) < 98304) {
            int n = j >> 8, k = j & 255;
            float v = (n < 128) ? c2r[(size_t)k * 128 + n]
                                : c2w[((size_t)((n >> 7) - 1) * 256 + k) * 128 + (n & 127)];
            wc2[(size_t)n * 256 + k] = f2bf(v);
        } else {
            j -= 98304;
            ((int4*)cnt)[j] = make_int4(0, 0, 0, 0);
        }
    }
}

// ---------------------------------------------------------------------------
// CSR build: histogram -> exclusive scan (3 kernels) -> fill
// ---------------------------------------------------------------------------
__global__ void hist_kernel(const int* __restrict__ dst, const int* __restrict__ et,
                            int* __restrict__ cnt) {
    int e = blockIdx.x * 256 + threadIdx.x;
    if (e < N_EDGES) atomicAdd(&cnt[et[e] * N_NODES + dst[e]], 1);
}

__global__ __launch_bounds__(1024) void scan1_kernel(const int* __restrict__ cnt,
                                                     int* __restrict__ ptr,
                                                     int* __restrict__ aux) {
    __shared__ int s[1024];
    int i = blockIdx.x * 1024 + threadIdx.x;
    int v = (i < NBINS) ? cnt[i] : 0;
    s[threadIdx.x] = v;
    __syncthreads();
    for (int off = 1; off < 1024; off <<= 1) {
        int t = (threadIdx.x >= off) ? s[threadIdx.x - off] : 0;
        __syncthreads();
        s[threadIdx.x] += t;
        __syncthreads();
    }
    if (i < NBINS) ptr[i] = s[threadIdx.x] - v;          // block-exclusive
    if (threadIdx.x == 1023) aux[blockIdx.x] = s[1023];  // block total
}

__global__ void scan2_kernel(int* __restrict__ aux, int nblk) {
    __shared__ int s[256];
    int v = (threadIdx.x < nblk) ? aux[threadIdx.x] : 0;
    s[threadIdx.x] = v;
    __syncthreads();
    for (int off = 1; off < 256; off <<= 1) {
        int t = (threadIdx.x >= off) ? s[threadIdx.x - off] : 0;
        __syncthreads();
        s[threadIdx.x] += t;
        __syncthreads();
    }
    if (threadIdx.x < nblk) aux[threadIdx.x] = s[threadIdx.x] - v;  // exclusive
}

__global__ void scan3_kernel(const int* __restrict__ aux, int* __restrict__ ptr,
                             int* __restrict__ cursor) {
    int i = blockIdx.x * 256 + threadIdx.x;
    if (i < NBINS) {
        int val = ptr[i] + aux[i >> 10];
        ptr[i] = val;
        cursor[i] = val;
    }
    if (i == 0) ptr[NBINS] = N_EDGES;
}

__global__ void fill_kernel(const int* __restrict__ src, const int* __restrict__ dst,
                            const int* __restrict__ et, int* __restrict__ cursor,
                            int* __restrict__ esorted) {
    int e = blockIdx.x * 256 + threadIdx.x;
    if (e < N_EDGES) {
        int b = et[e] * N_NODES + dst[e];
        int pos = atomicAdd(&cursor[b], 1);
        esorted[pos] = src[e];
    }
}

// ---------------------------------------------------------------------------
// Layer-1 gather-mean: one wave per TWO dst nodes (2 independent latency
// chains in flight), both relations, k-step-2 (8 guarded loads per iter).
// ---------------------------------------------------------------------------
__global__ void gather1_kernel(const int* __restrict__ ptr, const int* __restrict__ es,
                               ushort* __restrict__ A1) {
    int d0 = (blockIdx.x * 4 + (threadIdx.x >> 6)) * 2;
    if (d0 >= N_NODES) return;
    int lane = threadIdx.x & 63;
    int p0[2], n0[2], q0[2], n1[2];
#pragma unroll
    for (int u = 0; u < 2; u++) {
        p0[u] = ptr[d0 + u];           n0[u] = ptr[d0 + u + 1] - p0[u];
        q0[u] = ptr[N_NODES + d0 + u]; n1[u] = ptr[N_NODES + d0 + u + 1] - q0[u];
    }
    float a0[2] = {0, 0}, a1[2] = {0, 0}, b0[2] = {0, 0}, b1[2] = {0, 0};
    int n = n0[0] > n0[1] ? n0[0] : n0[1];
    int m2 = n1[0] > n1[1] ? n1[0] : n1[1];
    n = n > m2 ? n : m2;
    for (int k = 0; k < n; k += 2) {
        uint v0[2] = {0, 0}, v1[2] = {0, 0}, v2[2] = {0, 0}, v3[2] = {0, 0};
#pragma unroll
        for (int u = 0; u < 2; u++) {
            if (k     < n0[u]) v0[u] = *(const uint*)(A1 + (size_t)es[p0[u] + k]     * 384 + lane * 2);
            if (k + 1 < n0[u]) v1[u] = *(const uint*)(A1 + (size_t)es[p0[u] + k + 1] * 384 + lane * 2);
            if (k     < n1[u]) v2[u] = *(const uint*)(A1 + (size_t)es[q0[u] + k]     * 384 + lane * 2);
            if (k + 1 < n1[u]) v3[u] = *(const uint*)(A1 + (size_t)es[q0[u] + k + 1] * 384 + lane * 2);
        }
#pragma unroll
        for (int u = 0; u < 2; u++) {
            a0[u] += lo16(v0[u]) + lo16(v1[u]);
            a1[u] += hi16(v0[u]) + hi16(v1[u]);
            b0[u] += lo16(v2[u]) + lo16(v3[u]);
            b1[u] += hi16(v2[u]) + hi16(v3[u]);
        }
    }
#pragma unroll
    for (int u = 0; u < 2; u++) {
        float i0 = n0[u] ? 1.0f / (float)n0[u] : 0.0f;
        float i1 = n1[u] ? 1.0f / (float)n1[u] : 0.0f;
        uint* row = (uint*)(A1 + (size_t)(d0 + u) * 384);
        row[64  + lane] = packbf(a0[u] * i0, a1[u] * i0);
        row[128 + lane] = packbf(b0[u] * i1, b1[u] * i1);
    }
}

// ---------------------------------------------------------------------------
// Layer-2 combine: two dst nodes per wave.
// z[d] = H[d][0:128] + mean_r0 H[s][128:256] + mean_r1 H[s][256:384], bf16 out.
// ---------------------------------------------------------------------------
__global__ void combine2_kernel(const int* __restrict__ ptr, const int* __restrict__ es,
                                const ushort* __restrict__ H, ushort* __restrict__ zb) {
    int d0 = (blockIdx.x * 4 + (threadIdx.x >> 6)) * 2;
    if (d0 >= N_NODES) return;
    int lane = threadIdx.x & 63;
    int p0[2], n0[2], q0[2], n1[2];
#pragma unroll
    for (int u = 0; u < 2; u++) {
        p0[u] = ptr[d0 + u];           n0[u] = ptr[d0 + u + 1] - p0[u];
        q0[u] = ptr[N_NODES + d0 + u]; n1[u] = ptr[N_NODES + d0 + u + 1] - q0[u];
    }
    uint rv[2];
    rv[0] = *(const uint*)(H + (size_t)d0 * 384 + lane * 2);
    rv[1] = *(const uint*)(H + (size_t)(d0 + 1) * 384 + lane * 2);
    float a0[2] = {0, 0}, a1[2] = {0, 0}, b0[2] = {0, 0}, b1[2] = {0, 0};
    int n = n0[0] > n0[1] ? n0[0] : n0[1];
    int m2 = n1[0] > n1[1] ? n1[0] : n1[1];
    n = n > m2 ? n : m2;
    for (int k = 0; k < n; k += 2) {
        uint v0[2] = {0, 0}, v1[2] = {0, 0}, v2[2] = {0, 0}, v3[2] = {0, 0};
#pragma unroll
        for (int u = 0; u < 2; u++) {
            if (k     < n0[u]) v0[u] = *(const uint*)(H + (size_t)es[p0[u] + k]     * 384 + 128 + lane * 2);
            if (k + 1 < n0[u]) v1[u] = *(const uint*)(H + (size_t)es[p0[u] + k + 1] * 384 + 128 + lane * 2);
            if (k     < n1[u]) v2[u] = *(const uint*)(H + (size_t)es[q0[u] + k]     * 384 + 256 + lane * 2);
            if (k + 1 < n1[u]) v3[u] = *(const uint*)(H + (size_t)es[q0[u] + k + 1] * 384 + 256 + lane * 2);
        }
#pragma unroll
        for (int u = 0; u < 2; u++) {
            a0[u] += lo16(v0[u]) + lo16(v1[u]);
            a1[u] += hi16(v0[u]) + hi16(v1[u]);
            b0[u] += lo16(v2[u]) + lo16(v3[u]);
            b1[u] += hi16(v2[u]) + hi16(v3[u]);
        }
    }
#pragma unroll
    for (int u = 0; u < 2; u++) {
        float i0 = n0[u] ? 1.0f / (float)n0[u] : 0.0f;
        float i1 = n1[u] ? 1.0f / (float)n1[u] : 0.0f;
        ((uint*)(zb + (size_t)(d0 + u) * 128))[lane] =
            packbf(lo16(rv[u]) + a0[u] * i0 + b0[u] * i1,
                   hi16(rv[u]) + a1[u] * i0 + b1[u] * i1);
    }
}

// ---------------------------------------------------------------------------
// MFMA GEMM body (round-10 proven): 128x128 tile, 256 threads / 4 waves,
// 3-slot LDS pipeline with counted vmcnt, global_load_lds width-16,
// XOR-swizzled LDS. Standard operand order -> C cols = l15 -> 2B stores are
// lane-contiguous (coalesced 32B/16-lane segments).
// ---------------------------------------------------------------------------
template<int KTOT, int OST, int BIASN, bool RELU>
__device__ __forceinline__
void gemm_body(const ushort* __restrict__ A, const ushort* __restrict__ Wt,
               const float* __restrict__ bias, ushort* __restrict__ outp,
               int nrows, int m0, int n0) {
    __shared__ short As[3][128 * 32];
    __shared__ short Bs[3][128 * 32];
    const int t = threadIdx.x;
    const int lane = t & 63, w = t >> 6;
    const int wr = w >> 1, wc = w & 1;
    const int l15 = lane & 15, l4 = lane >> 4;

    const int arow = t >> 2;
    const int swc = ((t & 3) ^ ((arow >> 1) & 3)) * 8;
    int rg0 = m0 + arow;      if (rg0 >= nrows) rg0 = nrows - 1;
    int rg1 = m0 + arow + 64; if (rg1 >= nrows) rg1 = nrows - 1;
    const ushort* ap0 = A + (size_t)rg0 * KTOT + swc;
    const ushort* ap1 = A + (size_t)rg1 * KTOT + swc;
    const ushort* bp0 = Wt + (size_t)(n0 + arow) * KTOT + swc;
    const ushort* bp1 = Wt + (size_t)(n0 + arow + 64) * KTOT + swc;

#define STAGE(slot, kg) do { \
        GLDS16(ap0 + (kg), &As[slot][t * 8]); \
        GLDS16(ap1 + (kg), &As[slot][(t + 256) * 8]); \
        GLDS16(bp0 + (kg), &Bs[slot][t * 8]); \
        GLDS16(bp1 + (kg), &Bs[slot][(t + 256) * 8]); \
    } while (0)

    f32x4 acc[4][4];
#pragma unroll
    for (int j = 0; j < 4; j++) {
        int col = n0 + wc * 64 + j * 16 + l15;
        float bv = (col < BIASN) ? bias[col] : 0.0f;
        f32x4 tmp = {bv, bv, bv, bv};
#pragma unroll
        for (int i = 0; i < 4; i++) acc[i][j] = tmp;
    }

    const int xr = (l4 ^ ((l15 >> 1) & 3)) * 8;

    constexpr int NSTEP = KTOT / 32;
    STAGE(0, 0);
    if (NSTEP > 1) STAGE(1, 32);
    for (int ks = 0; ks < NSTEP; ks++) {
        const int slot = ks % 3;
        if (ks + 2 < NSTEP) {
            STAGE((ks + 2) % 3, (ks + 2) * 32);
            waitvm<8>();
        } else if (ks + 1 < NSTEP) {
            waitvm<4>();
        } else {
            waitvm<0>();
        }
        asm volatile("s_barrier" ::: "memory");
        short8_t af[4], bfr[4];
#pragma unroll
        for (int i = 0; i < 4; i++)
            af[i] = *(short8_t*)&As[slot][(wr * 64 + i * 16 + l15) * 32 + xr];
#pragma unroll
        for (int j = 0; j < 4; j++)
            bfr[j] = *(short8_t*)&Bs[slot][(wc * 64 + j * 16 + l15) * 32 + xr];
#pragma unroll
        for (int i = 0; i < 4; i++)
#pragma unroll
            for (int j = 0; j < 4; j++)
                acc[i][j] = __builtin_amdgcn_mfma_f32_16x16x32_bf16(af[i], bfr[j], acc[i][j], 0, 0, 0);
        asm volatile("s_barrier" ::: "memory");
    }
#undef STAGE

#pragma unroll
    for (int i = 0; i < 4; i++) {
#pragma unroll
        for (int r2 = 0; r2 < 4; r2++) {
            int row = m0 + wr * 64 + i * 16 + l4 * 4 + r2;
            if (row < nrows) {
#pragma unroll
                for (int j = 0; j < 4; j++) {
                    int col = n0 + wc * 64 + j * 16 + l15;
                    float v = acc[i][j][r2];
                    if (RELU) v = fmaxf(v, 0.0f);
                    outp[(size_t)row * OST + col] = f2bf(v);
                }
            }
        }
    }
}

// GEMM wrapper with XCD-bijective swizzle + N-panel-fastest work order.
template<int KTOT, int NP, int OST, int BIASN, bool RELU>
__global__ __launch_bounds__(256)
void mfma_gemm_kernel(const ushort* __restrict__ A, const ushort* __restrict__ Wt,
                      const float* __restrict__ bias, ushort* __restrict__ outp,
                      int nrows, int mtiles) {
    const int nwg = mtiles * NP;
    const int q = nwg >> 3, r = nwg & 7;
    const int orig = blockIdx.x;
    const int xcd = orig & 7;
    const int work = (xcd < r ? xcd * (q + 1) : r * (q + 1) + (xcd - r) * q) + (orig >> 3);
    const int mt = work / NP;
    gemm_body<KTOT, OST, BIASN, RELU>(A, Wt, bias, outp, nrows,
                                      mt * 128, (work - mt * NP) * 128);
}

// Both input projections in one launch: blocks [0,391) type0 (K=128),
// [391,782) type1 (K=64). Output into A1 x-slab (stride 384).
__global__ __launch_bounds__(256)
void proj_kernel(const ushort* __restrict__ x0bf, const ushort* __restrict__ x1bf,
                 const ushort* __restrict__ wl0, const ushort* __restrict__ wl1,
                 const float* __restrict__ l0b, const float* __restrict__ l1b,
                 ushort* __restrict__ A1) {
    if (blockIdx.x < 391)
        gemm_body<128, 384, 128, false>(x0bf, wl0, l0b, A1, 50000,
                                        blockIdx.x * 128, 0);
    else
        gemm_body<64, 384, 128, false>(x1bf, wl1, l1b, A1 + (size_t)50000 * 384, 50000,
                                       (blockIdx.x - 391) * 128, 0);
}

// ---------------------------------------------------------------------------
// Decode: two pairs per wave (4 independent row loads in flight).
// ---------------------------------------------------------------------------
__global__ void decode_kernel(const ushort* __restrict__ zb, const int* __restrict__ dec,
                              const float* __restrict__ fcw, const float* __restrict__ fcb,
                              float* __restrict__ out) {
    int p0 = (blockIdx.x * 4 + (threadIdx.x >> 6)) * 2;
    if (p0 >= N_PAIRS) return;
    int lane = threadIdx.x & 63;
    float ws0 = fcw[2 * lane],       ws1 = fcw[2 * lane + 1];
    float wd0 = fcw[128 + 2 * lane], wd1 = fcw[128 + 2 * lane + 1];
    int s0 = dec[p0],     dd0 = dec[N_PAIRS + p0];
    int s1 = dec[p0 + 1], dd1 = dec[N_PAIRS + p0 + 1];
    uint vs0 = ((const uint*)(zb + (size_t)s0  * 128))[lane];
    uint vd0 = ((const uint*)(zb + (size_t)dd0 * 128))[lane];
    uint vs1 = ((const uint*)(zb + (size_t)s1  * 128))[lane];
    uint vd1 = ((const uint*)(zb + (size_t)dd1 * 128))[lane];
    float v0 = lo16(vs0) * ws0 + hi16(vs0) * ws1 + lo16(vd0) * wd0 + hi16(vd0) * wd1;
    float v1 = lo16(vs1) * ws0 + hi16(vs1) * ws1 + lo16(vd1) * wd0 + hi16(vd1) * wd1;
#pragma unroll
    for (int off = 32; off > 0; off >>= 1) {
        v0 += __shfl_down(v0, off);
        v1 += __shfl_down(v1, off);
    }
    if (lane == 0) {
        float fb = fcb[0];
        out[p0]     = 1.0f / (1.0f + expf(-(v0 + fb)));
        out[p0 + 1] = 1.0f / (1.0f + expf(-(v1 + fb)));
    }
}

// ---------------------------------------------------------------------------
extern "C" void kernel_launch(void* const* d_in, const int* in_sizes, int n_in,
                              void* d_out, int out_size, void* d_ws, size_t ws_size,
                              hipStream_t stream) {
    const float* x0        = (const float*)d_in[0];
    const float* x1        = (const float*)d_in[1];
    const int*   edge_idx  = (const int*)  d_in[2];
    const int*   edge_type = (const int*)  d_in[3];
    const int*   dec_index = (const int*)  d_in[4];
    const float* lin0_w    = (const float*)d_in[5];
    const float* lin0_b    = (const float*)d_in[6];
    const float* lin1_w    = (const float*)d_in[7];
    const float* lin1_b    = (const float*)d_in[8];
    const float* conv1_w   = (const float*)d_in[9];
    const float* conv1_root= (const float*)d_in[10];
    const float* conv1_b   = (const float*)d_in[11];
    const float* conv2_w   = (const float*)d_in[12];
    const float* conv2_root= (const float*)d_in[13];
    const float* conv2_b   = (const float*)d_in[14];
    const float* fc_w      = (const float*)d_in[15];
    const float* fc_b      = (const float*)d_in[16];
    float* out = (float*)d_out;

    // ---- workspace layout (bytes), ~151.6 MB; H aliases A1, zb aliases y1 ----
    char* W = (char*)d_ws;
    ushort* A1    = (ushort*)(W + 0);            // 76,800,000 B [100k][384] = [x|agg0|agg1]
    ushort* H     = (ushort*)(W + 0);            // alias (A1 dead after gemm1)
    ushort* y1    = (ushort*)(W + 76800000);     // 51,200,000 B [100k][256]
    ushort* zb    = (ushort*)(W + 76800000);     // alias: [100k][128] bf16 (y1 dead after gemm2)
    int*    cnt   = (int*)   (W + 128000000);
    int*    ptrb  = (int*)   (W + 128800000);
    int*    cursor= (int*)   (W + 129600016);
    int*    aux   = (int*)   (W + 130400016);
    int*    esort = (int*)   (W + 130404112);
    ushort* wc1   = (ushort*)(W + 132004112);    // [256][384] bf16
    ushort* wc2   = (ushort*)(W + 132200720);    // [384][256] bf16
    ushort* wl0   = (ushort*)(W + 132397328);    // [128][128] bf16
    ushort* wl1   = (ushort*)(W + 132430096);    // [128][64]  bf16
    ushort* x0bf  = (ushort*)(W + 132446480);    // [50000][128] bf16
    ushort* x1bf  = (ushort*)(W + 145246480);    // [50000][64]  bf16

    const int* esrc = edge_idx;
    const int* edst = edge_idx + N_EDGES;

    // 1) fused prep: casts, weight repacks, cnt zero
    prep_kernel<<<2048, 256, 0, stream>>>(x0, x1, lin0_w, lin1_w,
                                          conv1_root, conv1_w, conv2_root, conv2_w,
                                          x0bf, x1bf, wl0, wl1, wc1, wc2, cnt);

    // 2) CSR build over (rel,dst)
    hist_kernel<<<(N_EDGES + 255) / 256, 256, 0, stream>>>(edst, edge_type, cnt);
    scan1_kernel<<<(NBINS + 1023) / 1024, 1024, 0, stream>>>(cnt, ptrb, aux);
    scan2_kernel<<<1, 256, 0, stream>>>(aux, (NBINS + 1023) / 1024);
    scan3_kernel<<<(NBINS + 255) / 256, 256, 0, stream>>>(aux, ptrb, cursor);
    fill_kernel<<<(N_EDGES + 255) / 256, 256, 0, stream>>>(esrc, edst, edge_type,
                                                           cursor, esort);

    // 3) both input projections -> A1 x-slab (cols 0:128, stride 384)
    proj_kernel<<<782, 256, 0, stream>>>(x0bf, x1bf, wl0, wl1, lin0_b, lin1_b, A1);

    // 4) layer 1: per-dst gather-mean into A1 agg slabs, then GEMM+ReLU -> y1
    gather1_kernel<<<12500, 256, 0, stream>>>(ptrb, esort, A1);
    mfma_gemm_kernel<384, 2, 256, 256, true>
        <<<1564, 256, 0, stream>>>(A1, wc1, conv1_b, y1, N_NODES, 782);

    // 5) layer 2: GEMM y1 @ [root2|W0|W1] -> H (aliases A1), then combine -> zb
    mfma_gemm_kernel<256, 3, 384, 128, false>
        <<<2346, 256, 0, stream>>>(y1, wc2, conv2_b, H, N_NODES, 782);
    combine2_kernel<<<12500, 256, 0, stream>>>(ptrb, esort, H, zb);

    // 6) decode
    decode_kernel<<<12500, 256, 0, stream>>>(zb, dec_index, fc_w, fc_b, out);
}